// Round 8
// baseline (847.518 us; speedup 1.0000x reference)
//
#include <hip/hip_runtime.h>
#include <cstdint>
#include <cstddef>

// ---------------------------------------------------------------------------
// AlphaNet: features -> BN -> conv(1x3,16) -> relu -> fc1(43200->512) -> relu
//          -> fc2(512->128) -> sigmoid -> fc3(128->1)
// R17: fused conv+GEMM repaired.
//   - conv restructured: thread=(row,k-half), 4 f16x8 units, ds_write_b128 at
//     swizzled slots (conflict-free; was 8-way on 8.29M cycles).
//   - OS-switch (os = k0%10, wave-uniform, 5 even values) -> fully static
//     conv_emit<OS>: no guards, no runtime indexing, no divides in the body.
//   - weights: block K-window spans <=2 ocs (verified all sk) -> preload 2
//     sets, per-decade cndmask select.
//   - feat loads issued at iter top + sched_barrier(0) pin; CONV between MMA
//     clusters 2 and 3 under vmcnt(4); one vmcnt(0)+lgkm(0)+barrier per tile.
// ---------------------------------------------------------------------------

typedef _Float16 f16;
typedef f16 f16x2 __attribute__((ext_vector_type(2)));
typedef f16 f16x8 __attribute__((ext_vector_type(8)));
typedef float f32x4 __attribute__((ext_vector_type(4)));

#define CHUNK   2048               // samples per GEMM pass (2 passes)
#define NTOT    4096
#define K_FC1   43200              // 16*270*10
#define KT_TOT  675                // K-tiles of 64
#define TILE_F  16384              // f16 per (tile,kt): 256 rows x 64 k
#define HALF_F  8192               // f16 per half-tile: 128 rows x 64 k
#define FPS     3240               // feat floats per sample

__device__ __forceinline__ float fillv(float x) { return isfinite(x) ? x : 0.0f; }

// static component select on float4 (folds at compile time for static I)
#define FEL(Q, I) ((I) == 0 ? (Q).x : (I) == 1 ? (Q).y : (I) == 2 ? (Q).z : (Q).w)

// ---------------------------------------------------------------------------
// conv_emit<OS>: 32 outputs (k = kbase..kbase+31, kbase%10 == OS's origin),
// decades di=0..3 with per-decade weights; 4 ds_write_b128.
// fr[12] = 4 decade rows x 3 float4 (12 cols each). All indices static.
// ---------------------------------------------------------------------------
template<int OS>
__device__ __forceinline__ void conv_emit(const float4 fr[12],
    const float W0[4], const float W1[4], const float W2[4], const float BZ[4],
    f16* dst, int c0, int crsw)
{
    #pragma unroll
    for (int ci = 0; ci < 4; ++ci) {
        f16x8 o;
        #pragma unroll
        for (int e = 0; e < 8; ++e) {
            const int p  = OS + ci * 8 + e;      // compile-time
            const int di = p / 10;               // 0..3
            const int wo = p - di * 10;          // 0..9
            float v0 = FEL(fr[di * 3 + ((wo    ) >> 2)], (wo    ) & 3);
            float v1 = FEL(fr[di * 3 + ((wo + 1) >> 2)], (wo + 1) & 3);
            float v2 = FEL(fr[di * 3 + ((wo + 2) >> 2)], (wo + 2) & 3);
            float y = fmaf(W2[di], v2, fmaf(W1[di], v1, fmaf(W0[di], v0, BZ[di])));
            y = fminf(fmaxf(y, 0.f) * 0.00390625f, 65000.f);
            o[e] = (f16)y;
        }
        *(f16x8*)(dst + (((c0 + ci) ^ crsw) << 3)) = o;
    }
}

// ---------------------------------------------------------------------------
// Kernel 1: fc1_w fp32 -> f16, retiled to [nt(2)][kt(675)][half(2)][128][64]
// with 16B-chunk swizzle: logical chunk c of row r stored at slot c ^ (r&7).
// ---------------------------------------------------------------------------
__global__ __launch_bounds__(256) void retile_w(const float* __restrict__ w,
                                                f16* __restrict__ Wt) {
    const int bid = blockIdx.x;               // nt*675 + kt
    const int nt = bid / KT_TOT, kt = bid % KT_TOT;
    const int t = threadIdx.x;
    f16* dst = Wt + (size_t)bid * TILE_F;
    #pragma unroll
    for (int j = 0; j < 8; ++j) {
        int q = t + 256 * j;                  // 0..2047 16B units
        int half = q >> 10, rr = (q >> 3) & 127, c = q & 7;
        const float* s = w + (size_t)(nt * 256 + half * 128 + rr) * K_FC1 + kt * 64 + c * 8;
        float4 x = *(const float4*)s;
        float4 y = *(const float4*)(s + 4);
        f16x8 o = { (f16)x.x, (f16)x.y, (f16)x.z, (f16)x.w,
                    (f16)y.x, (f16)y.y, (f16)y.z, (f16)y.w };
        int p = c ^ (rr & 7);
        *(f16x8*)(dst + (size_t)half * HALF_F + rr * 64 + p * 8) = o;
    }
}

// ---------------------------------------------------------------------------
// Kernel 2: feat_k — per-sample features, BN folded in, -> FEAT[n][3240] f32.
// ---------------------------------------------------------------------------
__global__ __launch_bounds__(256) void feat_k(
    const float* __restrict__ data, const float* __restrict__ bn_g,
    const float* __restrict__ bn_b, const float* __restrict__ bn_m,
    const float* __restrict__ bn_v, float* __restrict__ FEAT)
{
    __shared__ __align__(16) float raw[1800];
    __shared__ __align__(16) float feat[FPS];
    __shared__ int   pi[105], pj[105];

    const int t = threadIdx.x;
    const int n = blockIdx.x;
    const float4* src4 = (const float4*)(data + (size_t)n * 1800);
    for (int i = t; i < 450; i += 256) ((float4*)raw)[i] = src4[i];
    if (t < 105) {                               // triu_indices(15, k=1) order
        int i = 0, rem = t;
        while (rem >= 14 - i) { rem -= 14 - i; ++i; }
        pi[t] = i; pj[t] = i + 1 + rem;
    }
    __syncthreads();

    if (t < 180) {
        int f = t / 12, w = t % 12;
        int base = f * 120 + w * 10;
        const float2* r2 = (const float2*)(raw + base);
        float2 p0 = r2[0], p1 = r2[1], p2 = r2[2], p3 = r2[3], p4 = r2[4];
        float x[10] = { p0.x, p0.y, p1.x, p1.y, p2.x, p2.y, p3.x, p3.y, p4.x, p4.y };
        float sum = 0.f;
        #pragma unroll
        for (int s = 0; s < 10; ++s) sum += x[s];
        float mean = sum * 0.1f;
        float ret = x[9] / x[0] - 1.0f;
        float dl = 0.f;
        #pragma unroll
        for (int s = 0; s < 10; ++s) dl += x[s] * ((float)(s + 1) * (1.0f / 55.0f));
        float var = 0.f;
        float d[10];
        #pragma unroll
        for (int s = 0; s < 10; ++s) { d[s] = x[s] - mean; var += d[s] * d[s]; }
        float2* w2p = (float2*)(raw + base);
        #pragma unroll
        for (int s = 0; s < 5; ++s) w2p[s] = make_float2(d[2 * s], d[2 * s + 1]);
        var *= (1.0f / 9.0f);                    // unbiased
        float sd = sqrtf(var);
        feat[(210 + f) * 12 + w] = fillv(sd);
        feat[(225 + f) * 12 + w] = fillv(mean / sd);
        feat[(240 + f) * 12 + w] = fillv(ret);
        feat[(255 + f) * 12 + w] = fillv(dl);
    }
    __syncthreads();

    for (int q = t; q < 1260; q += 256) {
        int p = q / 12, w = q % 12;
        int i = pi[p], j = pj[p];
        const float2* ri = (const float2*)(raw + i * 120 + w * 10);
        const float2* rj = (const float2*)(raw + j * 120 + w * 10);
        float cv = 0.f;
        #pragma unroll
        for (int s = 0; s < 5; ++s) {
            float2 ai = ri[s], aj = rj[s];
            cv += ai.x * aj.x + ai.y * aj.y;
        }
        cv *= (1.0f / 9.0f);
        float si = feat[(210 + i) * 12 + w], sj = feat[(210 + j) * 12 + w];
        feat[p * 12 + w]         = fillv(cv / (si * sj) * 0.9f);  // *(S-1)/S
        feat[(105 + p) * 12 + w] = fillv(cv);
    }
    __syncthreads();

    // BN (C=1 scalar) folded into FEAT at store: feat' = a*feat + bb
    float a  = bn_g[0] * rsqrtf(bn_v[0] + 1e-5f);
    float bb = bn_b[0] - bn_m[0] * a;
    float4* dst = (float4*)(FEAT + (size_t)n * FPS);
    for (int i = t; i < FPS / 4; i += 256) {
        float4 v = ((const float4*)feat)[i];
        v.x = fmaf(v.x, a, bb); v.y = fmaf(v.y, a, bb);
        v.z = fmaf(v.z, a, bb); v.w = fmaf(v.w, a, bb);
        dst[i] = v;
    }
}

// ---------------------------------------------------------------------------
// Kernel 3: fused conv + fc1 GEMM.  Ysum[CHUNK,512] (+)= relu(conv(FEAT)) * W^T
// 256x256 tile, BK=64, 8 waves. A built in LDS from FEAT (conflict-free b128
// writes, static conv); B staged via gload_lds. 1 barrier/tile.
// mt = bid&7 -> XCD-pinned feat slice (3.3 MB, L2-resident).
// ---------------------------------------------------------------------------
__global__ __launch_bounds__(512, 2) void gemm_fused(
    const float* __restrict__ FEAT, const f16* __restrict__ W,
    const float* __restrict__ cw, const float* __restrict__ cb,
    float* __restrict__ Ysum, int n0)
{
    extern __shared__ f16 lds[];   // [0,32768): A bufs; [32768,65536): B bufs

    const int bid = blockIdx.x;                   // 256 blocks
    const int mt = bid & 7;                       // XCD-pinned M-tile
    const int slot = bid >> 3;
    const int nt = slot & 1;
    const int sk = slot >> 1;                     // 0..15
    const int kt0 = sk * 42 + (sk < 3 ? sk : 3);  // uneven split: 3x43 + 13x42
    const int cnt = 42 + (sk < 3 ? 1 : 0);

    const int tid = threadIdx.x;
    const int wave = tid >> 6, lane = tid & 63;
    const int quad = lane >> 4, m16 = lane & 15;
    const int rsw = m16 & 7;
    const int wm = (wave & 1) << 6;               // 0 / 64
    const int wn = (wave >> 1) << 5;              // 0/32/64/96

    // conv role: thread owns row cr, k-half dp (chunks 4dp..4dp+3). dp is
    // wave-uniform (waves 0-3: dp=0, waves 4-7: dp=1).
    const int cr = tid & 255, dp = tid >> 8;
    const int crsw = cr & 7, c0 = dp << 2;
    const float* featN = FEAT + (size_t)(n0 + mt * 256 + cr) * FPS;

    // two oc weight sets cover the whole block K-window (verified all sk)
    const int oc0 = (kt0 * 64) / 2700;
    const int ocb = oc0 + 1 < 16 ? oc0 + 1 : 15;
    const int thr = (oc0 + 1) * 270;              // decade threshold for set b
    const float w0a = cw[oc0 * 3], w1a = cw[oc0 * 3 + 1], w2a = cw[oc0 * 3 + 2];
    const float bza = cb[oc0];
    const float w0b = cw[ocb * 3], w1b = cw[ocb * 3 + 1], w2b = cw[ocb * 3 + 2];
    const float bzb = cb[ocb];
    const int h0a = oc0 * 270;                    // h = d - h0a - (sel?270:0)

    const f16* Bb = W + (size_t)(nt * KT_TOT + kt0) * TILE_F;

    f32x4 acc[8][4] = {};
    f16x8 a[4][2], bA[2][2], bB[2][2];
    float4 fr[12];
    int ds_n = 0;                                 // decade base of prefetched tile

#define STAGE_B(BUF, KI) do {                                                  \
    const f16* g_ = Bb + (size_t)(KI) * TILE_F + tid * 8;                      \
    f16* l_ = lds + 32768 + (BUF) * TILE_F + tid * 8;                          \
    __builtin_amdgcn_global_load_lds(                                          \
        (const __attribute__((address_space(1))) void*)g_,                     \
        (__attribute__((address_space(3))) void*)l_, 16, 0, 0);                \
    __builtin_amdgcn_global_load_lds(                                          \
        (const __attribute__((address_space(1))) void*)(g_ + 4096),            \
        (__attribute__((address_space(3))) void*)(l_ + 4096), 16, 0, 0);       \
    __builtin_amdgcn_global_load_lds(                                          \
        (const __attribute__((address_space(1))) void*)(g_ + 8192),            \
        (__attribute__((address_space(3))) void*)(l_ + 8192), 16, 0, 0);       \
    __builtin_amdgcn_global_load_lds(                                          \
        (const __attribute__((address_space(1))) void*)(g_ + 12288),           \
        (__attribute__((address_space(3))) void*)(l_ + 12288), 16, 0, 0);      \
} while (0)

// issue 12 feat-row loads for tile KI (4 decade rows x 3 float4)
#define FLOAD(KI) do {                                                         \
    int kk_ = (kt0 + (KI)) * 64 + (dp << 5);                                   \
    ds_n = kk_ / 10;                                                           \
    _Pragma("unroll") for (int di_ = 0; di_ < 4; ++di_) {                      \
        int d_ = ds_n + di_;                                                   \
        int h_ = d_ - h0a - (d_ >= thr ? 270 : 0);                             \
        const float4* fp_ = (const float4*)(featN + h_ * 12);                  \
        fr[di_ * 3 + 0] = fp_[0];                                              \
        fr[di_ * 3 + 1] = fp_[1];                                              \
        fr[di_ * 3 + 2] = fp_[2];                                              \
    } } while (0)

// build A-subtile for tile KI into buf BUF (uses fr + ds_n from FLOAD(KI))
#define CONV(BUF, KI) do {                                                     \
    float W0_[4], W1_[4], W2_[4], BZ_[4];                                      \
    _Pragma("unroll") for (int di_ = 0; di_ < 4; ++di_) {                      \
        bool s_ = (ds_n + di_) >= thr;                                         \
        W0_[di_] = s_ ? w0b : w0a; W1_[di_] = s_ ? w1b : w1a;                  \
        W2_[di_] = s_ ? w2b : w2a; BZ_[di_] = s_ ? bzb : bza;                  \
    }                                                                          \
    int os_ = (kt0 + (KI)) * 64 + (dp << 5) - ds_n * 10;                       \
    f16* dst_ = lds + (BUF) * TILE_F + (cr >> 7) * HALF_F + (size_t)(cr & 127) * 64; \
    switch (os_ >> 1) {                                                        \
        case 0: conv_emit<0>(fr, W0_, W1_, W2_, BZ_, dst_, c0, crsw); break;   \
        case 1: conv_emit<2>(fr, W0_, W1_, W2_, BZ_, dst_, c0, crsw); break;   \
        case 2: conv_emit<4>(fr, W0_, W1_, W2_, BZ_, dst_, c0, crsw); break;   \
        case 3: conv_emit<6>(fr, W0_, W1_, W2_, BZ_, dst_, c0, crsw); break;   \
        default: conv_emit<8>(fr, W0_, W1_, W2_, BZ_, dst_, c0, crsw); break;  \
    } } while (0)

#define RD_A(MH, BUF) do {                                                     \
    _Pragma("unroll") for (int i2_ = 0; i2_ < 4; ++i2_)                        \
    _Pragma("unroll") for (int kh_ = 0; kh_ < 2; ++kh_)                        \
        a[i2_][kh_] = *(const f16x8*)(lds + (BUF) * TILE_F + (MH) * HALF_F     \
            + (wm + i2_ * 16 + m16) * 64 + (((kh_ * 4 + quad) ^ rsw) << 3));   \
} while (0)

#define RD_B(DST, NH, BUF) do {                                                \
    _Pragma("unroll") for (int j2_ = 0; j2_ < 2; ++j2_)                        \
    _Pragma("unroll") for (int kh_ = 0; kh_ < 2; ++kh_)                        \
        DST[j2_][kh_] = *(const f16x8*)(lds + 32768 + (BUF) * TILE_F           \
            + (NH) * HALF_F                                                    \
            + (wn + j2_ * 16 + m16) * 64 + (((kh_ * 4 + quad) ^ rsw) << 3));   \
} while (0)

#define MMA(IO, JO, BF) do {                                                   \
    _Pragma("unroll") for (int i2_ = 0; i2_ < 4; ++i2_)                        \
    _Pragma("unroll") for (int j2_ = 0; j2_ < 2; ++j2_)                        \
    _Pragma("unroll") for (int kh_ = 0; kh_ < 2; ++kh_)                        \
        acc[(IO) + i2_][(JO) + j2_] = __builtin_amdgcn_mfma_f32_16x16x32_f16(  \
            a[i2_][kh_], BF[j2_][kh_], acc[(IO) + i2_][(JO) + j2_], 0, 0, 0);  \
} while (0)

    // prologue: B-tile 0 async; A-tile 0 from FEAT
    STAGE_B(0, 0);
    FLOAD(0);
    CONV(0, 0);                                   // compiler waits fr deps
    asm volatile("s_waitcnt vmcnt(0) lgkmcnt(0)" ::: "memory");
    __builtin_amdgcn_s_barrier();

    #pragma unroll 1
    for (int ti = 0; ti < cnt; ++ti) {
        const int bc = ti & 1, bn = bc ^ 1;
        if (ti + 1 < cnt) {
            FLOAD(ti + 1);                        // 12 feat loads (oldest)
            STAGE_B(bn, ti + 1);                  // 4 gload_lds
            __builtin_amdgcn_sched_barrier(0);    // pin load issue early
        }
        RD_A(0, bc); RD_B(bA, 0, bc);
        __builtin_amdgcn_s_setprio(1);
        MMA(0, 0, bA);
        __builtin_amdgcn_s_setprio(0);
        RD_B(bB, 1, bc);
        __builtin_amdgcn_s_setprio(1);
        MMA(0, 2, bB);
        __builtin_amdgcn_s_setprio(0);
        if (ti + 1 < cnt) {
            asm volatile("s_waitcnt vmcnt(4)" ::: "memory");  // feat landed
            CONV(bn, ti + 1);                     // build A(bn); writes != reads(bc)
        }
        RD_A(1, bc);
        __builtin_amdgcn_s_setprio(1);
        MMA(4, 2, bB);
        MMA(4, 0, bA);
        __builtin_amdgcn_s_setprio(0);
        if (ti + 1 < cnt) {
            asm volatile("s_waitcnt vmcnt(0) lgkmcnt(0)" ::: "memory");
            __builtin_amdgcn_s_barrier();         // publish bn; retire bc
        }
    }

#undef STAGE_B
#undef FLOAD
#undef CONV
#undef RD_A
#undef RD_B
#undef MMA

    // C/D layout: col = lane&15, row = quad*4 + reg. Atomic split-K reduce.
    float* Yb = Ysum + (size_t)(mt * 256) * 512 + nt * 256;
    #pragma unroll
    for (int i = 0; i < 8; ++i) {
        const int row0 = (i >> 2) * 128 + wm + (i & 3) * 16 + quad * 4;
        #pragma unroll
        for (int j = 0; j < 4; ++j) {
            const int col = (j >> 1) * 128 + wn + (j & 1) * 16 + m16;
            #pragma unroll
            for (int r = 0; r < 4; ++r)
                unsafeAtomicAdd(&Yb[(size_t)(row0 + r) * 512 + col], acc[i][j][r]);
        }
    }
}

// ---------------------------------------------------------------------------
// Kernel 4: head = (relu(sum*256+b1)) -> fc2 + sigmoid -> fc3
// ---------------------------------------------------------------------------
__global__ __launch_bounds__(128) void head_fc23(const float* __restrict__ y1s,
                                                 const float* __restrict__ b1,
                                                 const float* __restrict__ w2,
                                                 const float* __restrict__ b2,
                                                 const float* __restrict__ w3,
                                                 const float* __restrict__ b3,
                                                 float* __restrict__ out, int n0)
{
    __shared__ float Ys[8 * 512];    // 16 KB
    __shared__ float Y2[8 * 128];    // 4 KB
    const int t = threadIdx.x;
    const float4* yb = (const float4*)(y1s + (size_t)blockIdx.x * 8 * 512);
    const float4* b1v = (const float4*)b1;
    for (int i = t; i < 8 * 128; i += 128) {
        float4 s = yb[i];
        float4 bv = b1v[i & 127];
        float4 y;
        y.x = fmaxf(fmaf(s.x, 256.f, bv.x), 0.f);
        y.y = fmaxf(fmaf(s.y, 256.f, bv.y), 0.f);
        y.z = fmaxf(fmaf(s.z, 256.f, bv.z), 0.f);
        y.w = fmaxf(fmaf(s.w, 256.f, bv.w), 0.f);
        ((float4*)Ys)[i] = y;
    }
    __syncthreads();

    float acc[8];
    float bk = b2[t];
    #pragma unroll
    for (int s = 0; s < 8; ++s) acc[s] = bk;
    const float4* wr = (const float4*)(w2 + (size_t)t * 512);
    for (int jc = 0; jc < 128; ++jc) {
        float4 w4 = wr[jc];
        #pragma unroll
        for (int s = 0; s < 8; ++s) {
            float4 y4 = *(const float4*)(Ys + s * 512 + jc * 4);
            acc[s] += w4.x * y4.x + w4.y * y4.y + w4.z * y4.z + w4.w * y4.w;
        }
    }
    #pragma unroll
    for (int s = 0; s < 8; ++s) Y2[s * 128 + t] = 1.0f / (1.0f + expf(-acc[s]));
    __syncthreads();

    if (t < 8) {
        float sm = b3[0];
        #pragma unroll 4
        for (int k = 0; k < 128; ++k) sm += Y2[t * 128 + k] * w3[k];
        out[n0 + blockIdx.x * 8 + t] = sm;
    }
}

// ---------------------------------------------------------------------------
extern "C" void kernel_launch(void* const* d_in, const int* in_sizes, int n_in,
                              void* d_out, int out_size, void* d_ws, size_t ws_size,
                              hipStream_t stream)
{
    const float* data = (const float*)d_in[0];
    const float* bn_g = (const float*)d_in[1];
    const float* bn_b = (const float*)d_in[2];
    const float* bn_m = (const float*)d_in[3];
    const float* bn_v = (const float*)d_in[4];
    const float* cw   = (const float*)d_in[5];
    const float* cb   = (const float*)d_in[6];
    const float* fc1w = (const float*)d_in[7];
    const float* fc1b = (const float*)d_in[8];
    const float* fc2w = (const float*)d_in[9];
    const float* fc2b = (const float*)d_in[10];
    const float* fc3w = (const float*)d_in[11];
    const float* fc3b = (const float*)d_in[12];
    float* out = (float*)d_out;

    // workspace layout: FEAT 53.1 MB + W16 44.2 MB + y1s 4.2 MB ~= 101.5 MB
    const size_t FEAT_BYTES = (size_t)NTOT * FPS * 4;         //  53,084,160
    const size_t W16_BYTES  = (size_t)512 * K_FC1 * 2;        //  44,236,800
    const size_t Y1_BYTES   = (size_t)CHUNK * 512 * 4;        //   4,194,304
    if (ws_size < FEAT_BYTES + W16_BYTES + Y1_BYTES) return;

    char* ws = (char*)d_ws;
    float* FEAT = (float*)ws;
    f16*   W16  = (f16*)(ws + FEAT_BYTES);
    float* y1s  = (float*)(ws + FEAT_BYTES + W16_BYTES);

    // one-time opt-in for 128 KiB dynamic LDS (gfx950 has 160 KiB/CU)
    static int smem_set = 0;
    if (!smem_set) {
        hipFuncSetAttribute(reinterpret_cast<const void*>(gemm_fused),
                            hipFuncAttributeMaxDynamicSharedMemorySize, 131072);
        smem_set = 1;
    }

    retile_w<<<2 * KT_TOT, 256, 0, stream>>>(fc1w, W16);
    feat_k<<<NTOT, 256, 0, stream>>>(data, bn_g, bn_b, bn_m, bn_v, FEAT);

    for (int c = 0; c < 2; ++c) {
        int n0 = c * CHUNK;
        hipMemsetAsync(y1s, 0, Y1_BYTES, stream);
        gemm_fused<<<256, 512, 131072, stream>>>(FEAT, W16, cw, cb, y1s, n0);
        head_fc23<<<CHUNK / 8, 128, 0, stream>>>(y1s, fc1b, fc2w, fc2b, fc3w, fc3b, out, n0);
    }
}

// Round 9
// 541.310 us; speedup vs baseline: 1.5657x; 1.5657x over previous
//
#include <hip/hip_runtime.h>
#include <cstdint>
#include <cstddef>

// ---------------------------------------------------------------------------
// AlphaNet: features -> BN -> conv(1x3,16) -> relu -> fc1(43200->512) -> relu
//          -> fc2(512->128) -> sigmoid -> fc3(128->1)
// R18: revert fused conv (R16 LDS-conflicts, R17 VGPR-spill: WRITE 67->174MB)
//   to the R15 pipeline, + stage_a conv phase rewritten to exploit row-major
//   A16: conv outputs go registers -> global directly (5 aligned f16x2 @20B
//   stride per item; lanes tile 1280B spans). cstage round-trip (27K LDS
//   ops/block) and 8 barriers eliminated; LDS 35.7->21.3KB (7 blocks/CU).
//   gemm_fc1 / retile_w / head byte-identical to R15.
// ---------------------------------------------------------------------------

typedef _Float16 f16;
typedef f16 f16x2 __attribute__((ext_vector_type(2)));
typedef f16 f16x8 __attribute__((ext_vector_type(8)));
typedef float f32x4 __attribute__((ext_vector_type(4)));

#define CHUNK   2048               // samples per pipeline pass (2 passes)
#define K_FC1   43200              // 16*270*10
#define KT_TOT  675                // K-tiles of 64
#define TILE_F  16384              // f16 per W (nt,kt) tile: 256 rows x 64 k
#define HALF_F  8192               // f16 per half-tile: 128 rows x 64 k

__device__ __forceinline__ float fillv(float x) { return isfinite(x) ? x : 0.0f; }

// ---------------------------------------------------------------------------
// Kernel 1: fc1_w fp32 -> f16, retiled to [nt(2)][kt(675)][half(2)][128][64]
// with 16B-chunk swizzle: logical chunk c of row r stored at slot c ^ (r&7).
// ---------------------------------------------------------------------------
__global__ __launch_bounds__(256) void retile_w(const float* __restrict__ w,
                                                f16* __restrict__ Wt) {
    const int bid = blockIdx.x;               // nt*675 + kt
    const int nt = bid / KT_TOT, kt = bid % KT_TOT;
    const int t = threadIdx.x;
    f16* dst = Wt + (size_t)bid * TILE_F;
    #pragma unroll
    for (int j = 0; j < 8; ++j) {
        int q = t + 256 * j;                  // 0..2047 16B units
        int half = q >> 10, rr = (q >> 3) & 127, c = q & 7;
        const float* s = w + (size_t)(nt * 256 + half * 128 + rr) * K_FC1 + kt * 64 + c * 8;
        float4 x = *(const float4*)s;
        float4 y = *(const float4*)(s + 4);
        f16x8 o = { (f16)x.x, (f16)x.y, (f16)x.z, (f16)x.w,
                    (f16)y.x, (f16)y.y, (f16)y.z, (f16)y.w };
        int p = c ^ (rr & 7);
        *(f16x8*)(dst + (size_t)half * HALF_F + rr * 64 + p * 8) = o;
    }
}

// ---------------------------------------------------------------------------
// Kernel 2: per-sample features + folded-BN conv + relu -> A16 (scaled 2^-8),
// plain row-major [sample][43200] f16. Conv phase: one flat loop, outputs
// straight to global (no LDS staging, no extra barriers).
// ---------------------------------------------------------------------------
__global__ __launch_bounds__(256) void stage_a(
    const float* __restrict__ data, const float* __restrict__ bn_g,
    const float* __restrict__ bn_b, const float* __restrict__ bn_m,
    const float* __restrict__ bn_v, const float* __restrict__ conv_w,
    const float* __restrict__ conv_b, f16* __restrict__ A16, int n0)
{
    __shared__ __align__(16) float raw[1800];     // raw windows -> spread
    __shared__ __align__(16) float feat[3240];
    __shared__ float cwf[48];          // BN-folded conv weights (a * cw)
    __shared__ float cbf[16];          // BN-folded conv bias
    __shared__ int   pi[105], pj[105];

    const int t = threadIdx.x;
    const int n = n0 + blockIdx.x;
    const float4* src4 = (const float4*)(data + (size_t)n * 1800);
    for (int i = t; i < 450; i += 256) ((float4*)raw)[i] = src4[i];

    // BN fold (C=1): feat_bn = a*feat + bb  =>  cw' = a*cw,
    // cb' = cb + bb*(cw0+cw1+cw2)
    {
        float a  = bn_g[0] * rsqrtf(bn_v[0] + 1e-5f);
        float bb = bn_b[0] - bn_m[0] * a;
        if (t < 48) cwf[t] = conv_w[t] * a;
        if (t < 16) cbf[t] = conv_b[t] + bb * (conv_w[3 * t] + conv_w[3 * t + 1] + conv_w[3 * t + 2]);
    }
    if (t < 105) {                               // triu_indices(15, k=1) order
        int i = 0, rem = t;
        while (rem >= 14 - i) { rem -= 14 - i; ++i; }
        pi[t] = i; pj[t] = i + 1 + rem;
    }
    __syncthreads();

    // per-(f,w) stats; overwrite raw with spread (float2 access, 8B aligned)
    if (t < 180) {
        int f = t / 12, w = t % 12;
        int base = f * 120 + w * 10;
        const float2* r2 = (const float2*)(raw + base);
        float2 p0 = r2[0], p1 = r2[1], p2 = r2[2], p3 = r2[3], p4 = r2[4];
        float x[10] = { p0.x, p0.y, p1.x, p1.y, p2.x, p2.y, p3.x, p3.y, p4.x, p4.y };
        float sum = 0.f;
        #pragma unroll
        for (int s = 0; s < 10; ++s) sum += x[s];
        float mean = sum * 0.1f;
        float ret = x[9] / x[0] - 1.0f;
        float dl = 0.f;
        #pragma unroll
        for (int s = 0; s < 10; ++s) dl += x[s] * ((float)(s + 1) * (1.0f / 55.0f));
        float var = 0.f;
        float d[10];
        #pragma unroll
        for (int s = 0; s < 10; ++s) { d[s] = x[s] - mean; var += d[s] * d[s]; }
        float2* w2p = (float2*)(raw + base);
        #pragma unroll
        for (int s = 0; s < 5; ++s) w2p[s] = make_float2(d[2 * s], d[2 * s + 1]);
        var *= (1.0f / 9.0f);                    // unbiased
        float sd = sqrtf(var);
        feat[(210 + f) * 12 + w] = fillv(sd);
        feat[(225 + f) * 12 + w] = fillv(mean / sd);
        feat[(240 + f) * 12 + w] = fillv(ret);
        feat[(255 + f) * 12 + w] = fillv(dl);
    }
    __syncthreads();

    // pairwise cov / corr (float2 reads of spread)
    for (int q = t; q < 1260; q += 256) {
        int p = q / 12, w = q % 12;
        int i = pi[p], j = pj[p];
        const float2* ri = (const float2*)(raw + i * 120 + w * 10);
        const float2* rj = (const float2*)(raw + j * 120 + w * 10);
        float cv = 0.f;
        #pragma unroll
        for (int s = 0; s < 5; ++s) {
            float2 ai = ri[s], aj = rj[s];
            cv += ai.x * aj.x + ai.y * aj.y;
        }
        cv *= (1.0f / 9.0f);
        float si = feat[(210 + i) * 12 + w], sj = feat[(210 + j) * 12 + w];
        feat[p * 12 + w]         = fillv(cv / (si * sj) * 0.9f);  // *(S-1)/S
        feat[(105 + p) * 12 + w] = fillv(cv);
    }
    __syncthreads();

    // conv(1x3) + bias + relu -> 2^-8 -> f16 -> DIRECT global stores.
    // item = oc*270 + h (consecutive lanes -> consecutive h: a wave's 5
    // f16x2 store insts tile a contiguous 1280B span). oc = item/270 via
    // magic mul (exact for item < 4320).
    f16* abase = A16 + (size_t)blockIdx.x * K_FC1;
    #pragma unroll
    for (int j = 0; j < 17; ++j) {
        int item = t + (j << 8);
        if (item < 4320) {
            int oc = (item * 971) >> 18;         // == item / 270
            int h  = item - oc * 270;
            const float4* f4 = (const float4*)(feat + h * 12);
            float4 fa = f4[0], fb = f4[1], fc = f4[2];
            float fv[12] = { fa.x, fa.y, fa.z, fa.w,
                             fb.x, fb.y, fb.z, fb.w,
                             fc.x, fc.y, fc.z, fc.w };
            float w0 = cwf[oc * 3], w1 = cwf[oc * 3 + 1], w2 = cwf[oc * 3 + 2];
            float bz = cbf[oc];
            f16* dst = abase + oc * 2700 + h * 10;   // byte addr % 4 == 0
            #pragma unroll
            for (int q = 0; q < 5; ++q) {
                float y0 = fmaf(w2, fv[2 * q + 2], fmaf(w1, fv[2 * q + 1], fmaf(w0, fv[2 * q], bz)));
                float y1 = fmaf(w2, fv[2 * q + 3], fmaf(w1, fv[2 * q + 2], fmaf(w0, fv[2 * q + 1], bz)));
                y0 = fminf(fmaxf(y0, 0.f) * 0.00390625f, 65000.f);
                y1 = fminf(fmaxf(y1, 0.f) * 0.00390625f, 65000.f);
                *(f16x2*)(dst + 2 * q) = f16x2{ (f16)y0, (f16)y1 };
            }
        }
    }
}

// ---------------------------------------------------------------------------
// Kernel 3: fc1 GEMM  Ysum[CHUNK,512] (+)= A * W^T (f16 MFMA)
// 4-phase schedule: 256x256 tile, BK=64, 8 waves (512 thr); counted vmcnt(4);
// setprio around MFMA clusters; LDS 128 KiB dynamic -> 1 block/CU, grid 256.
// mt = bid>>5 -> XCD (= bid&7) groups the 8 mt-blocks sharing one W K-window
// (W slice L2-resident; FETCH -65 MB verified R14).
// A row-major; STAGE_A per-lane pre-swizzled source (R15-verified).
// ---------------------------------------------------------------------------
__global__ __launch_bounds__(512, 2) void gemm_fc1(const f16* __restrict__ A,
                                                   const f16* __restrict__ W,
                                                   float* __restrict__ Ysum)
{
    extern __shared__ f16 lds[];   // [0,32768): A bufs; [32768,65536): B bufs

    const int bid = blockIdx.x;                   // 256 blocks
    const int mt = bid >> 5;                      // 0..7  M-tile
    const int slot = bid & 31;                    // (nt,sk) -> XCD = slot&7
    const int nt = slot & 1;
    const int sk = slot >> 1;                     // 0..15
    const int kt0 = sk * 42 + (sk < 3 ? sk : 3);  // uneven split: 3x43 + 13x42
    const int cnt = 42 + (sk < 3 ? 1 : 0);

    const int tid = threadIdx.x;
    const int wave = tid >> 6, lane = tid & 63;
    const int quad = lane >> 4, m16 = lane & 15;
    const int rsw = m16 & 7;                      // row&7 == m16&7 (bases = 0 mod 8)
    const int wm = (wave & 1) << 6;               // 0 / 64   (row slice in each half)
    const int wn = (wave >> 1) << 5;              // 0/32/64/96 (col slice in each half)

    // per-lane staging source for A (row-major): row = tid>>3, chunk = tid&7,
    // source k-chunk = chunk ^ (row&7)  -> LDS[row][chunk] = A[row][swz chunk]
    const int s_row = tid >> 3, s_ch = tid & 7;
    const f16* A_l = A + (size_t)(mt * 256 + s_row) * K_FC1 + (size_t)kt0 * 64
                       + ((s_ch ^ (s_row & 7)) << 3);
    const f16* Bb = W + (size_t)(nt * KT_TOT + kt0) * TILE_F;

    f32x4 acc[8][4] = {};
    f16x8 a[4][2], bA[2][2], bB[2][2];

#define STAGE_A(BUF, HALF, KI) do {                                            \
    const f16* g_ = A_l + (size_t)(HALF) * 128 * K_FC1 + (size_t)(KI) * 64;    \
    f16* l_ = lds + (BUF) * TILE_F + (HALF) * HALF_F + tid * 8;                \
    __builtin_amdgcn_global_load_lds(                                          \
        (const __attribute__((address_space(1))) void*)g_,                     \
        (__attribute__((address_space(3))) void*)l_, 16, 0, 0);                \
    __builtin_amdgcn_global_load_lds(                                          \
        (const __attribute__((address_space(1))) void*)(g_ + (size_t)64 * K_FC1), \
        (__attribute__((address_space(3))) void*)(l_ + 4096), 16, 0, 0);       \
} while (0)

#define STAGE_B(BUF, HALF, KI) do {                                            \
    const f16* g_ = Bb + (size_t)(KI) * TILE_F + (HALF) * HALF_F + tid * 8;    \
    f16* l_ = lds + 32768 + (BUF) * TILE_F + (HALF) * HALF_F + tid * 8;        \
    __builtin_amdgcn_global_load_lds(                                          \
        (const __attribute__((address_space(1))) void*)g_,                     \
        (__attribute__((address_space(3))) void*)l_, 16, 0, 0);                \
    __builtin_amdgcn_global_load_lds(                                          \
        (const __attribute__((address_space(1))) void*)(g_ + 4096),            \
        (__attribute__((address_space(3))) void*)(l_ + 4096), 16, 0, 0);       \
} while (0)

#define RD_A(MH, BUF) do {                                                     \
    _Pragma("unroll") for (int i2_ = 0; i2_ < 4; ++i2_)                        \
    _Pragma("unroll") for (int kh_ = 0; kh_ < 2; ++kh_)                        \
        a[i2_][kh_] = *(const f16x8*)(lds + (BUF) * TILE_F + (MH) * HALF_F     \
            + (wm + i2_ * 16 + m16) * 64 + (((kh_ * 4 + quad) ^ rsw) << 3));   \
} while (0)

#define RD_B(DST, NH, BUF) do {                                                \
    _Pragma("unroll") for (int j2_ = 0; j2_ < 2; ++j2_)                        \
    _Pragma("unroll") for (int kh_ = 0; kh_ < 2; ++kh_)                        \
        DST[j2_][kh_] = *(const f16x8*)(lds + 32768 + (BUF) * TILE_F           \
            + (NH) * HALF_F                                                    \
            + (wn + j2_ * 16 + m16) * 64 + (((kh_ * 4 + quad) ^ rsw) << 3));   \
} while (0)

#define MMA(IO, JO, BF) do {                                                   \
    _Pragma("unroll") for (int i2_ = 0; i2_ < 4; ++i2_)                        \
    _Pragma("unroll") for (int j2_ = 0; j2_ < 2; ++j2_)                        \
    _Pragma("unroll") for (int kh_ = 0; kh_ < 2; ++kh_)                        \
        acc[(IO) + i2_][(JO) + j2_] = __builtin_amdgcn_mfma_f32_16x16x32_f16(  \
            a[i2_][kh_], BF[j2_][kh_], acc[(IO) + i2_][(JO) + j2_], 0, 0, 0);  \
} while (0)

    // prologue: stage tile 0 into buf 0 (order h0=A0, h1=B0, h2=B1, h3=A1)
    STAGE_A(0, 0, 0);
    STAGE_B(0, 0, 0);
    STAGE_B(0, 1, 0);
    STAGE_A(0, 1, 0);
    asm volatile("s_waitcnt vmcnt(4)" ::: "memory");  // h0,h1 landed
    __builtin_amdgcn_s_barrier();

    #pragma unroll 1
    for (int ti = 0; ti < cnt - 1; ++ti) {
        const int bc = ti & 1, bn = bc ^ 1;
        // ---- P1: quad(Mhalf0, Nhalf0); prefetch next A-half0 (h0')
        RD_A(0, bc); RD_B(bA, 0, bc);
        STAGE_A(bn, 0, ti + 1);
        __builtin_amdgcn_s_barrier();
        __builtin_amdgcn_s_setprio(1);
        MMA(0, 0, bA);
        __builtin_amdgcn_s_setprio(0);
        asm volatile("s_waitcnt vmcnt(4)" ::: "memory");  // h2 (B1) landed
        __builtin_amdgcn_s_barrier();
        // ---- P2: quad(0,1); prefetch next B-half0 (h1')
        RD_B(bB, 1, bc);
        STAGE_B(bn, 0, ti + 1);
        __builtin_amdgcn_s_barrier();
        __builtin_amdgcn_s_setprio(1);
        MMA(0, 2, bB);
        __builtin_amdgcn_s_setprio(0);
        asm volatile("s_waitcnt vmcnt(4)" ::: "memory");  // h3 (A1) landed
        __builtin_amdgcn_s_barrier();
        // ---- P3: quad(1,1); prefetch next B-half1 (h2')
        RD_A(1, bc);
        STAGE_B(bn, 1, ti + 1);
        __builtin_amdgcn_s_barrier();
        __builtin_amdgcn_s_setprio(1);
        MMA(4, 2, bB);
        __builtin_amdgcn_s_setprio(0);
        __builtin_amdgcn_s_barrier();
        // ---- P4: quad(1,0) from regs; prefetch next A-half1 (h3')
        STAGE_A(bn, 1, ti + 1);
        __builtin_amdgcn_s_barrier();
        __builtin_amdgcn_s_setprio(1);
        MMA(4, 0, bA);
        __builtin_amdgcn_s_setprio(0);
        asm volatile("s_waitcnt vmcnt(4)" ::: "memory");  // h0',h1' landed
        __builtin_amdgcn_s_barrier();
    }

    // epilogue tile (no prefetch; drains vmcnt once)
    {
        const int bc = (cnt - 1) & 1;
        RD_A(0, bc); RD_B(bA, 0, bc);
        __builtin_amdgcn_s_setprio(1);
        MMA(0, 0, bA);
        __builtin_amdgcn_s_setprio(0);
        asm volatile("s_waitcnt vmcnt(2)" ::: "memory");  // h2 landed
        __builtin_amdgcn_s_barrier();
        RD_B(bB, 1, bc);
        __builtin_amdgcn_s_setprio(1);
        MMA(0, 2, bB);
        __builtin_amdgcn_s_setprio(0);
        asm volatile("s_waitcnt vmcnt(0)" ::: "memory");  // h3 landed
        __builtin_amdgcn_s_barrier();
        RD_A(1, bc);
        __builtin_amdgcn_s_setprio(1);
        MMA(4, 2, bB);
        MMA(4, 0, bA);
        __builtin_amdgcn_s_setprio(0);
    }

#undef STAGE_A
#undef STAGE_B
#undef RD_A
#undef RD_B
#undef MMA

    // C/D layout: col = lane&15, row = quad*4 + reg. Atomic split-K reduce.
    // acc[i][j]: row half = i>>2, row frag = i&3; col half = j>>1, frag = j&1.
    float* Yb = Ysum + (size_t)(mt * 256) * 512 + nt * 256;
    #pragma unroll
    for (int i = 0; i < 8; ++i) {
        const int row0 = (i >> 2) * 128 + wm + (i & 3) * 16 + quad * 4;
        #pragma unroll
        for (int j = 0; j < 4; ++j) {
            const int col = (j >> 1) * 128 + wn + (j & 1) * 16 + m16;
            #pragma unroll
            for (int r = 0; r < 4; ++r)
                unsafeAtomicAdd(&Yb[(size_t)(row0 + r) * 512 + col], acc[i][j][r]);
        }
    }
}

// ---------------------------------------------------------------------------
// Kernel 4: head = (relu(sum*256+b1)) -> fc2 + sigmoid -> fc3
// 8 samples/block, 128 threads -> 256 blocks per chunk.
// ---------------------------------------------------------------------------
__global__ __launch_bounds__(128) void head_fc23(const float* __restrict__ y1s,
                                                 const float* __restrict__ b1,
                                                 const float* __restrict__ w2,
                                                 const float* __restrict__ b2,
                                                 const float* __restrict__ w3,
                                                 const float* __restrict__ b3,
                                                 float* __restrict__ out, int n0)
{
    __shared__ float Ys[8 * 512];    // 16 KB
    __shared__ float Y2[8 * 128];    // 4 KB
    const int t = threadIdx.x;
    const float4* yb = (const float4*)(y1s + (size_t)blockIdx.x * 8 * 512);
    const float4* b1v = (const float4*)b1;
    for (int i = t; i < 8 * 128; i += 128) {
        float4 s = yb[i];
        float4 bv = b1v[i & 127];
        float4 y;
        y.x = fmaxf(fmaf(s.x, 256.f, bv.x), 0.f);
        y.y = fmaxf(fmaf(s.y, 256.f, bv.y), 0.f);
        y.z = fmaxf(fmaf(s.z, 256.f, bv.z), 0.f);
        y.w = fmaxf(fmaf(s.w, 256.f, bv.w), 0.f);
        ((float4*)Ys)[i] = y;
    }
    __syncthreads();

    float acc[8];
    float bk = b2[t];
    #pragma unroll
    for (int s = 0; s < 8; ++s) acc[s] = bk;
    const float4* wr = (const float4*)(w2 + (size_t)t * 512);
    for (int jc = 0; jc < 128; ++jc) {
        float4 w4 = wr[jc];
        #pragma unroll
        for (int s = 0; s < 8; ++s) {
            float4 y4 = *(const float4*)(Ys + s * 512 + jc * 4);
            acc[s] += w4.x * y4.x + w4.y * y4.y + w4.z * y4.z + w4.w * y4.w;
        }
    }
    #pragma unroll
    for (int s = 0; s < 8; ++s) Y2[s * 128 + t] = 1.0f / (1.0f + expf(-acc[s]));
    __syncthreads();

    if (t < 8) {
        float sm = b3[0];
        #pragma unroll 4
        for (int k = 0; k < 128; ++k) sm += Y2[t * 128 + k] * w3[k];
        out[n0 + blockIdx.x * 8 + t] = sm;
    }
}

// ---------------------------------------------------------------------------
extern "C" void kernel_launch(void* const* d_in, const int* in_sizes, int n_in,
                              void* d_out, int out_size, void* d_ws, size_t ws_size,
                              hipStream_t stream)
{
    const float* data = (const float*)d_in[0];
    const float* bn_g = (const float*)d_in[1];
    const float* bn_b = (const float*)d_in[2];
    const float* bn_m = (const float*)d_in[3];
    const float* bn_v = (const float*)d_in[4];
    const float* cw   = (const float*)d_in[5];
    const float* cb   = (const float*)d_in[6];
    const float* fc1w = (const float*)d_in[7];
    const float* fc1b = (const float*)d_in[8];
    const float* fc2w = (const float*)d_in[9];
    const float* fc2b = (const float*)d_in[10];
    const float* fc3w = (const float*)d_in[11];
    const float* fc3b = (const float*)d_in[12];
    float* out = (float*)d_out;

    // workspace layout (total ~225.6 MB, known-safe)
    const size_t A16_BYTES = (size_t)CHUNK * K_FC1 * 2;       // 176,947,200
    const size_t W16_BYTES = (size_t)512 * K_FC1 * 2;         //  44,236,800
    const size_t Y1_BYTES  = (size_t)CHUNK * 512 * 4;         //   4,194,304
    if (ws_size < A16_BYTES + W16_BYTES + Y1_BYTES) return;

    char* ws = (char*)d_ws;
    f16*   A16 = (f16*)ws;
    f16*   W16 = (f16*)(ws + A16_BYTES);
    float* y1s = (float*)(ws + A16_BYTES + W16_BYTES);

    // one-time opt-in for 128 KiB dynamic LDS (gfx950 has 160 KiB/CU)
    static int smem_set = 0;
    if (!smem_set) {
        hipFuncSetAttribute(reinterpret_cast<const void*>(gemm_fc1),
                            hipFuncAttributeMaxDynamicSharedMemorySize, 131072);
        smem_set = 1;
    }

    retile_w<<<2 * KT_TOT, 256, 0, stream>>>(fc1w, W16);

    for (int c = 0; c < 2; ++c) {
        int n0 = c * CHUNK;
        hipMemsetAsync(y1s, 0, Y1_BYTES, stream);
        stage_a<<<CHUNK, 256, 0, stream>>>(data, bn_g, bn_b, bn_m, bn_v, cw, cb, A16, n0);
        gemm_fc1<<<256, 512, 131072, stream>>>(A16, W16, y1s);
        head_fc23<<<CHUNK / 8, 128, 0, stream>>>(y1s, fc1b, fc2w, fc2b, fc3w, fc3b, out, n0);
    }
}